// Round 11
// baseline (56.248 us; speedup 1.0000x reference)
//
#include <hip/hip_runtime.h>
#include <hip/hip_bf16.h>

#define NH 8
#define DH 32
#define LW 256
#define HW 4096
#define CIN 256

typedef float f32x4 __attribute__((ext_vector_type(4)));
typedef short s16x8 __attribute__((ext_vector_type(8)));
typedef short s16x4 __attribute__((ext_vector_type(4)));

#define AS1 __attribute__((address_space(1)))
#define AS3 __attribute__((address_space(3)))

__device__ __forceinline__ short f2bf(float f) {
  __hip_bfloat16 h = __float2bfloat16(f);   // RNE
  short s; __builtin_memcpy(&s, &h, 2); return s;
}

__device__ __forceinline__ void gload_lds16(const void* g, void* l) {
  __builtin_amdgcn_global_load_lds((const AS1 void*)g, (AS3 void*)l, 16, 0, 0);
}

// ws layout (bf16 shorts):
//   Q_ws / K_ws: [kb=d>>3][l 256][d&7 8] per window     @ 0 / KOFF
//   V_ws:        [d 32][l 256] per window               @ VOFF
//   feaB (BsV image): [t3][b4][pblk32][kb32][p^swz 128][8]   @ FBOFF  (24MB)
//   WtB  (AsV image): [t3][oblk4][cs4][o64][(kb^(o&7))8][8]  @ WT2OFF (384KB)
#define KOFF 4194304
#define VOFF 8388608
#define FBOFF 12582912
#define WT2OFF 25165824

// ---------------- prep kernel: f32 -> bf16 LDS-image layouts ----------------
// blocks 0..383: fea (t,b,pblk); blocks 384..395: W (t,oblk). Pure streaming.
__global__ void __launch_bounds__(256, 4)
prep_kernel(const float* __restrict__ fq, const float* __restrict__ fk,
            const float* __restrict__ fv,
            const float* __restrict__ qw, const float* __restrict__ kw,
            const float* __restrict__ vw, short* __restrict__ ws) {
  int blk = blockIdx.x;
  int tid = threadIdx.x;
  if (blk < 384) {
    int t = blk >> 7, b = (blk >> 5) & 3, pblk = blk & 31;
    const float* fea = (t == 0) ? fq : ((t == 1) ? fk : fv);
    const float* feab = fea + b * (CIN * HW);
    short* dstblk = ws + FBOFF + (((t * 4 + b) * 32 + pblk)) * 32768;
    int coct = tid >> 5, pq = (tid & 31) * 4;
#pragma unroll
    for (int cs = 0; cs < 4; ++cs) {
      f32x4 ld[8];
#pragma unroll
      for (int j = 0; j < 8; ++j)
        ld[j] = *(const f32x4*)(feab + (cs * 64 + coct * 8 + j) * HW + pblk * 128 + pq);
#pragma unroll
      for (int pp = 0; pp < 4; ++pp) {
        s16x8 v;
#pragma unroll
        for (int j = 0; j < 8; ++j) v[j] = f2bf(ld[j][pp]);
        int p = pq + pp;
        int pidx = p ^ ((p >> 3) & 7);
        *(s16x8*)(dstblk + ((cs * 8 + coct) * 128 + pidx) * 8) = v;
      }
    }
  } else {
    int idx = blk - 384;
    int t = idx >> 2, oblk = idx & 3, o0 = oblk * 64;
    const float* Wm = (t == 0) ? qw : ((t == 1) ? kw : vw);
    short* wdst = ws + WT2OFF + idx * 16384;
#pragma unroll
    for (int cs = 0; cs < 4; ++cs) {
#pragma unroll
      for (int i = 0; i < 2; ++i) {
        int ch = i * 256 + tid;
        int o = ch >> 3, kb2 = ch & 7;
        const float* src = Wm + (o0 + o) * CIN + cs * 64 + kb2 * 8;
        f32x4 w0 = *(const f32x4*)(src);
        f32x4 w1 = *(const f32x4*)(src + 4);
        s16x8 v;
#pragma unroll
        for (int j = 0; j < 4; ++j) { v[j] = f2bf(w0[j]); v[4 + j] = f2bf(w1[j]); }
        *(s16x8*)(wdst + cs * 4096 + (o * 8 + (kb2 ^ (o & 7))) * 8) = v;
      }
    }
  }
}

// ---------------- projection kernel ----------------
// tile BM=64(o) x BN=128(p) x BK=64; 4 waves. Both operands DMA'd to LDS via
// global_load_lds (bf16 images from prep), double-buffered, counted vmcnt.
__global__ void __launch_bounds__(256, 3)
proj_kernel(const float* __restrict__ qb, const float* __restrict__ kb_,
            const float* __restrict__ vb, short* __restrict__ ws) {
  __shared__ s16x8 SMEM[3072];      // 48KB: buf{0,1} x (A 512 + B 1024); epilogue reuses as Tr

  int bid = blockIdx.x;
  int orig = (bid & 7) * 192 + (bid >> 3);   // XCD-chunked swizzle (1536 = 8*192)
  int t = orig >> 9;                         // 0:Q 1:K 2:V
  int r0 = orig & 511;
  int b = r0 >> 7;
  int pblk = (r0 >> 2) & 31;
  int oblk = r0 & 3;

  const float* Bv = (t == 0) ? qb : ((t == 1) ? kb_ : vb);

  int p0 = pblk * 128, o0 = oblk * 64;
  int tid = threadIdx.x;
  int lane = tid & 63, wv = tid >> 6;
  int g = lane >> 4, li = lane & 15;

  const short* feaBblk = ws + FBOFF + ((t * 4 + b) * 32 + pblk) * 32768;
  const short* wtblk   = ws + WT2OFF + (t * 4 + oblk) * 16384;

  const f32x4 fzero = {0.f, 0.f, 0.f, 0.f};
  f32x4 acc[8];
#pragma unroll
  for (int n = 0; n < 8; ++n) acc[n] = fzero;

  // bias early, fully drained so in-loop vmcnt counts stay exact
  int od = o0 + wv * 16 + g * 4;
  float bias_r[4];
#pragma unroll
  for (int rr = 0; rr < 4; ++rr) bias_r[rr] = Bv[od + rr];
  asm volatile("s_waitcnt vmcnt(0)" ::: "memory");
  __builtin_amdgcn_sched_barrier(0);

  // STAGE: 6 gload_lds16 per wave (A: 2 segs of 8, B: 4 segs of 16)
#define STAGE(cs_, buf_) do { \
    const short* as_ = wtblk + (cs_) * 4096; \
    s16x8* ad_ = SMEM + (buf_) * 1536; \
    _Pragma("unroll") \
    for (int i_ = 0; i_ < 2; ++i_) { int seg_ = i_ * 4 + wv; \
      gload_lds16(as_ + (seg_ * 64 + lane) * 8, ad_ + seg_ * 64); } \
    const short* bs_ = feaBblk + (cs_) * 8192; \
    s16x8* bd_ = SMEM + (buf_) * 1536 + 512; \
    _Pragma("unroll") \
    for (int i_ = 0; i_ < 4; ++i_) { int seg_ = i_ * 4 + wv; \
      gload_lds16(bs_ + (seg_ * 64 + lane) * 8, bd_ + seg_ * 64); } } while (0)

  STAGE(0, 0);

#pragma unroll
  for (int cs = 0; cs < 4; ++cs) {
    if (cs < 3) STAGE(cs + 1, (cs + 1) & 1);
    if (cs < 3) { asm volatile("s_waitcnt vmcnt(6)" ::: "memory"); }
    else        { asm volatile("s_waitcnt vmcnt(0)" ::: "memory"); }
    __builtin_amdgcn_sched_barrier(0);
    __builtin_amdgcn_s_barrier();
    __builtin_amdgcn_sched_barrier(0);
    const s16x8* Abuf = SMEM + (cs & 1) * 1536;
    const s16x8* Bbuf = Abuf + 512;
#pragma unroll
    for (int kk = 0; kk < 2; ++kk) {
      int or0 = wv * 16 + li;
      s16x8 a0 = Abuf[or0 * 8 + ((kk * 4 + g) ^ (or0 & 7))];
#pragma unroll
      for (int n = 0; n < 8; ++n) {
        int p = n * 16 + li;
        int pidx = p ^ ((p >> 3) & 7);
        s16x8 bb = Bbuf[(kk * 4 + g) * 128 + pidx];
        acc[n] = __builtin_amdgcn_mfma_f32_16x16x32_bf16(a0, bb, acc[n], 0, 0, 0);
      }
    }
    __builtin_amdgcn_sched_barrier(0);
    __builtin_amdgcn_s_barrier();
    __builtin_amdgcn_sched_barrier(0);
  }
#undef STAGE

  // epilogue: bias + scatter into window layouts in ws (bf16)  [r10-verbatim]
  if (t != 2) {
    int nh = od >> 5;
    int kb = (od & 31) >> 3;
    int dlo = od & 7;
#pragma unroll
    for (int n = 0; n < 8; ++n) {
      int p = p0 + n * 16 + li;
      int h = p >> 6, w = p & 63;
      int s1 = h & 3, h0 = h >> 2, s2 = w & 3, w0 = w >> 2;
      int wwin = s1 * 4 + s2, l = h0 * 16 + w0;
      int winbase = (b * NH + nh) * 16 + wwin;
      s16x4 v;
#pragma unroll
      for (int rr = 0; rr < 4; ++rr) v[rr] = f2bf(acc[n][rr] + bias_r[rr]);
      short* dst = ws + (t == 0 ? 0 : KOFF);
      *(s16x4*)(dst + winbase * 8192 + (kb * 256 + l) * 8 + dlo) = v;
    }
  } else {
    short* Tr = (short*)SMEM;             // [p_local 128][o_local^swz 64]  16KB
    int ob = wv * 16 + g * 4;
#pragma unroll
    for (int n = 0; n < 8; ++n) {
      int p = n * 16 + li;
      s16x4 v;
#pragma unroll
      for (int rr = 0; rr < 4; ++rr) v[rr] = f2bf(acc[n][rr] + bias_r[rr]);
      *(s16x4*)(Tr + p * 64 + (ob ^ ((p & 15) << 2))) = v;
    }
    __syncthreads();
    int o_local = tid >> 2;
    int sub = tid & 3;
    int h_idx = sub >> 1;
    int woct = sub & 1;
    int o = o0 + o_local;
    int nh2 = o >> 5, d = o & 31;
    int hh = (p0 >> 6) + h_idx;
    int s1e = hh & 3, h0e = hh >> 2;
#pragma unroll
    for (int s2e = 0; s2e < 4; ++s2e) {
      s16x8 v;
#pragma unroll
      for (int k = 0; k < 8; ++k) {
        int pl = h_idx * 64 + s2e + 32 * woct + 4 * k;
        v[k] = Tr[pl * 64 + (o_local ^ ((pl & 15) << 2))];
      }
      int wwin = s1e * 4 + s2e;
      int l_oct = h0e * 2 + woct;
      int winbase = (b * NH + nh2) * 16 + wwin;
      *(s16x8*)(ws + VOFF + winbase * 8192 + d * 256 + l_oct * 8) = v;
    }
  }
}

// ---------------- attention kernel ----------------  [r10-verbatim]
__global__ void __launch_bounds__(256, 4)
attn_kernel(const short* __restrict__ ws, const float* __restrict__ mq,
            const float* __restrict__ mk, float* __restrict__ out) {
  __shared__ s16x8 KsV[1024];   // [kb4][l256]          16KB
  __shared__ s16x8 PsV[512];    // [wave][koct4][row32] 8KB
  __shared__ float amaskS[256];
  __shared__ float mqS[128];
  __shared__ float facS[128];
  __shared__ int anyS[4];

  int bid = blockIdx.x;
  int orig = (bid & 7) * 128 + (bid >> 3);   // XCD-chunked swizzle (1024 = 8*128)
  int qh = orig & 1;
  int s2 = (orig >> 1) & 3, s1 = (orig >> 3) & 3, nh = (orig >> 5) & 7, b = orig >> 8;
  int wwin = s1 * 4 + s2;
  int tid = threadIdx.x;
  int lane = tid & 63, wv = tid >> 6, g = lane >> 4, li = lane & 15;

  int winbase = (b * NH + nh) * 16 + wwin;
  const short* qt = ws + winbase * 8192;
  const short* kt = ws + KOFF + winbase * 8192;
  const short* vt = ws + VOFF + winbase * 8192;

#pragma unroll
  for (int i = 0; i < 4; ++i) {
    int seg = i * 4 + wv;
    gload_lds16(kt + (seg * 64 + lane) * 8, &KsV[seg * 64]);
  }

  {
    int l = tid;
    int h = (l >> 4) * 4 + s1, w = (l & 15) * 4 + s2;
    float mkv = mk[b * HW + h * 64 + w];
    amaskS[l] = (mkv > 0.5f) ? 0.0f : -1e30f;
    unsigned long long bal = __ballot(mkv > 0.5f);
    if (lane == 0) anyS[wv] = (bal != 0ULL) ? 1 : 0;
  }
  if (tid < 128) {
    int l = qh * 128 + tid;
    int h = (l >> 4) * 4 + s1, w = (l & 15) * 4 + s2;
    mqS[tid] = mq[b * HW + h * 64 + w];
  }

  int lq0 = wv * 32;
  s16x8 qa[2];
#pragma unroll
  for (int m = 0; m < 2; ++m)
    qa[m] = *(const s16x8*)(qt + (g * 256 + qh * 128 + lq0 + m * 16 + li) * 8);

  __syncthreads();
  int anyk = anyS[0] | anyS[1] | anyS[2] | anyS[3];

  const f32x4 fzero = {0.f, 0.f, 0.f, 0.f};
  f32x4 of[2][2];
#pragma unroll
  for (int m = 0; m < 2; ++m) { of[m][0] = fzero; of[m][1] = fzero; }
  float rs[8];
#pragma unroll
  for (int i = 0; i < 8; ++i) rs[i] = 0.0f;

  const float C = 0.17677669529663689f * 1.4426950408889634f;

#pragma unroll
  for (int lkb = 0; lkb < 4; ++lkb) {
    f32x4 sa[2][4];
#pragma unroll
    for (int n = 0; n < 4; ++n) {
      s16x8 kf = KsV[g * 256 + lkb * 64 + n * 16 + li];
#pragma unroll
      for (int m = 0; m < 2; ++m)
        sa[m][n] = __builtin_amdgcn_mfma_f32_16x16x32_bf16(qa[m], kf, fzero, 0, 0, 0);
    }
#pragma unroll
    for (int ks = 0; ks < 2; ++ks) {
#pragma unroll
      for (int n2 = 0; n2 < 2; ++n2) {
        int n = ks * 2 + n2;
        float am = amaskS[lkb * 64 + n * 16 + li];
#pragma unroll
        for (int m = 0; m < 2; ++m) {
#pragma unroll
          for (int rr = 0; rr < 4; ++rr) {
            float pval = exp2f(sa[m][n][rr] * C + am);
            rs[m * 4 + rr] += pval;
            int row = m * 16 + g * 4 + rr;
            int cl = n * 16 + li;
            int kbh = (cl >> 3) & 3;
            short* ps = (short*)&PsV[wv * 128 + kbh * 32 + row];
            ps[cl & 7] = f2bf(pval);
          }
        }
      }
      int kg = lkb * 2 + ks;
      s16x8 pb[2];
#pragma unroll
      for (int n = 0; n < 2; ++n) pb[n] = PsV[wv * 128 + g * 32 + n * 16 + li];
#pragma unroll
      for (int m2 = 0; m2 < 2; ++m2) {
        s16x8 va = *(const s16x8*)(vt + (m2 * 16 + li) * 256 + (kg * 4 + g) * 8);
#pragma unroll
        for (int n = 0; n < 2; ++n)
          of[m2][n] = __builtin_amdgcn_mfma_f32_16x16x32_bf16(va, pb[n], of[m2][n], 0, 0, 0);
      }
    }
  }

#pragma unroll
  for (int i = 0; i < 8; ++i) {
    float v = rs[i];
    v += __shfl_xor(v, 1);
    v += __shfl_xor(v, 2);
    v += __shfl_xor(v, 4);
    v += __shfl_xor(v, 8);
    rs[i] = v;
  }
  if (li == 0) {
#pragma unroll
    for (int m = 0; m < 2; ++m)
#pragma unroll
      for (int rr = 0; rr < 4; ++rr) {
        int row = m * 16 + g * 4 + rr;
        float sum = rs[m * 4 + rr];
        facS[wv * 32 + row] = (anyk && mqS[wv * 32 + row] > 0.5f) ? (1.0f / sum) : 0.0f;
      }
  }

#pragma unroll
  for (int m2 = 0; m2 < 2; ++m2) {
#pragma unroll
    for (int n = 0; n < 2; ++n) {
      int lloc = wv * 32 + n * 16;
      float fac = facS[lloc + li];
      int l = qh * 128 + lloc;
      int h = (l >> 4) * 4 + s1;
      int w = li * 4 + s2;
#pragma unroll
      for (int rr = 0; rr < 4; ++rr) {
        int o = nh * 32 + m2 * 16 + g * 4 + rr;
        out[((b * 256 + o) * 64 + h) * 64 + w] = of[m2][n][rr] * fac;
      }
    }
  }
}

extern "C" void kernel_launch(void* const* d_in, const int* in_sizes, int n_in,
                              void* d_out, int out_size, void* d_ws, size_t ws_size,
                              hipStream_t stream) {
  const float* fq = (const float*)d_in[0];
  const float* fk = (const float*)d_in[1];
  const float* fv = (const float*)d_in[2];
  const float* mq = (const float*)d_in[3];
  const float* mk = (const float*)d_in[4];
  const float* qw = (const float*)d_in[5];
  const float* qb = (const float*)d_in[6];
  const float* kw = (const float*)d_in[7];
  const float* kb = (const float*)d_in[8];
  const float* vw = (const float*)d_in[9];
  const float* vb = (const float*)d_in[10];
  short* ws = (short*)d_ws;   // Q[0,8M) K[8,16M) V[16,24M) feaB[24,48M) WtB[48,48.4M)

  prep_kernel<<<396, 256, 0, stream>>>(fq, fk, fv, qw, kw, vw, ws);
  proj_kernel<<<1536, 256, 0, stream>>>(qb, kb, vb, ws);
  attn_kernel<<<1024, 256, 0, stream>>>(ws, mq, mk, (float*)d_out);
}

// Round 12
// 48.601 us; speedup vs baseline: 1.1573x; 1.1573x over previous
//
#include <hip/hip_runtime.h>
#include <hip/hip_bf16.h>

#define NH 8
#define DH 32
#define LW 256
#define HW 4096
#define CIN 256

typedef float f32x4 __attribute__((ext_vector_type(4)));
typedef short s16x8 __attribute__((ext_vector_type(8)));
typedef short s16x4 __attribute__((ext_vector_type(4)));

#define AS1 __attribute__((address_space(1)))
#define AS3 __attribute__((address_space(3)))

__device__ __forceinline__ short f2bf(float f) {
  __hip_bfloat16 h = __float2bfloat16(f);   // RNE
  short s; __builtin_memcpy(&s, &h, 2); return s;
}

__device__ __forceinline__ void gload_lds16(const void* g, void* l) {
  __builtin_amdgcn_global_load_lds((const AS1 void*)g, (AS3 void*)l, 16, 0, 0);
}

// ws layouts (bf16 shorts), per window (winbase = (b*NH+nh)*16 + wwin, 8192 shorts/win):
//   Q_ws / K_ws: [kb=d>>3][l 256][d&7 8]
//   V_ws: fragment-ordered: idx = (l>>5)*1024 + ((l>>3)&3)*256 + (d>>4)*128 + (d&15)*8 + (l&7)
//   Wt (bf16 weights, k-major): [t 3][kb 32][o 256][8]  at WTOFF
#define KOFF 4194304
#define VOFF 8388608
#define WTOFF 12582912

// ---------------- weight pre-convert kernel ----------------
__global__ void wconv_kernel(const float* __restrict__ qw, const float* __restrict__ kw,
                             const float* __restrict__ vw, short* __restrict__ ws) {
  int blk = blockIdx.x;
  int t = blk >> 5, kb = blk & 31;
  const float* W = (t == 0) ? qw : ((t == 1) ? kw : vw);
  int o = threadIdx.x;
  f32x4 w0 = *(const f32x4*)(W + o * CIN + kb * 8);
  f32x4 w1 = *(const f32x4*)(W + o * CIN + kb * 8 + 4);
  s16x8 v;
#pragma unroll
  for (int j = 0; j < 4; ++j) { v[j] = f2bf(w0[j]); v[4 + j] = f2bf(w1[j]); }
  *(s16x8*)(ws + WTOFF + (blk * 256 + o) * 8) = v;
}

// ---------------- projection kernel ----------------
// tile BM=128(o) x BN=128(p) x BK=64; 4 waves; wave wv = head (nh = oblk*4+wv)
// A-fragments read DIRECTLY from Wt (L2-hot). B double-buffered in LDS.
// Epilogue: LDS transpose (stride-136) -> fully coalesced 16B stores for Q/K/V.
__global__ void __launch_bounds__(256, 3)
proj_kernel(const float* __restrict__ fq, const float* __restrict__ fk,
            const float* __restrict__ fv,
            const float* __restrict__ qb, const float* __restrict__ kb_,
            const float* __restrict__ vb,
            short* __restrict__ ws) {
  __shared__ s16x8 SMEM[2304];      // GEMM: B dbuf [2][1024] (32KB); epilogue: Tr [128][136] shorts (34.8KB)

  int bid = blockIdx.x;
  int orig = (bid & 7) * 96 + (bid >> 3);   // XCD-chunked swizzle (768 = 8*96)
  int t = orig >> 8;                        // 0:Q 1:K 2:V
  int r0 = orig & 255;
  int b = r0 >> 6;
  int pblk = (r0 >> 1) & 31;
  int oblk = r0 & 1;

  const float* fea = (t == 0) ? fq : ((t == 1) ? fk : fv);
  const float* Bv  = (t == 0) ? qb : ((t == 1) ? kb_ : vb);
  const short* Wt  = ws + WTOFF + t * 65536;   // [kb 32][o 256][8]

  int p0 = pblk * 128, o0 = oblk * 128;
  int tid = threadIdx.x;
  int lane = tid & 63, wv = tid >> 6;
  int g = lane >> 4, li = lane & 15;

  const f32x4 fzero = {0.f, 0.f, 0.f, 0.f};
  f32x4 acc[2][8];
#pragma unroll
  for (int m = 0; m < 2; ++m)
#pragma unroll
    for (int n = 0; n < 8; ++n) acc[m][n] = fzero;

  const float* feab = fea + b * (CIN * HW);
  int coct = tid >> 5;           // 0..7 (c octet)
  int pq = (tid & 31) * 4;       // p quad 0..124

  f32x4 ldB[8];

#define LOAD_B(cs_) do { int c0_ = (cs_) * 64; _Pragma("unroll") \
  for (int j_ = 0; j_ < 8; ++j_) \
    ldB[j_] = *(const f32x4*)(feab + (c0_ + coct * 8 + j_) * HW + p0 + pq); } while (0)

#define WRITE_B(buf_) do { _Pragma("unroll") \
  for (int pp_ = 0; pp_ < 4; ++pp_) { s16x8 v_; _Pragma("unroll") \
    for (int j_ = 0; j_ < 8; ++j_) v_[j_] = f2bf(ldB[j_][pp_]); \
    int p_ = pq + pp_; int pidx_ = p_ ^ ((p_ >> 3) & 7); \
    SMEM[(buf_) * 1024 + coct * 128 + pidx_] = v_; } } while (0)

  // prologue: fill buffer 0
  LOAD_B(0);
  WRITE_B(0);
  __syncthreads();

#pragma unroll
  for (int cs = 0; cs < 4; ++cs) {
    if (cs < 3) LOAD_B(cs + 1);
    // compute from buf[cs&1]; A-frags direct from Wt
#pragma unroll
    for (int kk = 0; kk < 2; ++kk) {
      int kbg = cs * 8 + kk * 4 + g;
      const short* abase = Wt + (kbg * 256 + o0 + wv * 32 + li) * 8;
      s16x8 a0 = *(const s16x8*)(abase);
      s16x8 a1 = *(const s16x8*)(abase + 128);
#pragma unroll
      for (int n = 0; n < 8; ++n) {
        int p = n * 16 + li;
        int pidx = p ^ ((p >> 3) & 7);
        s16x8 bb = SMEM[(cs & 1) * 1024 + (kk * 4 + g) * 128 + pidx];
        acc[0][n] = __builtin_amdgcn_mfma_f32_16x16x32_bf16(a0, bb, acc[0][n], 0, 0, 0);
        acc[1][n] = __builtin_amdgcn_mfma_f32_16x16x32_bf16(a1, bb, acc[1][n], 0, 0, 0);
      }
    }
    if (cs < 3) {
      WRITE_B((cs + 1) & 1);
      __syncthreads();
    }
  }
#undef LOAD_B
#undef WRITE_B

  // ---- epilogue: bias + LDS transpose (stride 136) + coalesced 16B stores ----
  float bias_r[2][4];
#pragma unroll
  for (int m = 0; m < 2; ++m)
#pragma unroll
    for (int rr = 0; rr < 4; ++rr)
      bias_r[m][rr] = Bv[o0 + wv * 32 + m * 16 + g * 4 + rr];

  __syncthreads();                      // all LDS reads of last chunk done
  short* Tr = (short*)SMEM;             // [p 128][o 128] row stride 136 shorts
#pragma unroll
  for (int m = 0; m < 2; ++m) {
    int ob = wv * 32 + m * 16 + g * 4;
#pragma unroll
    for (int n = 0; n < 8; ++n) {
      int p = n * 16 + li;
      s16x4 v;
#pragma unroll
      for (int rr = 0; rr < 4; ++rr) v[rr] = f2bf(acc[m][n][rr] + bias_r[m][rr]);
      *(s16x4*)(Tr + p * 136 + ob) = v;
    }
  }
  __syncthreads();

  if (t != 2) {
    // Q/K: lane = one l, 8 consecutive d -> 16B store; lanes 4-apart fill 64B lines
    short* dst = ws + (t == 0 ? 0 : KOFF);
#pragma unroll
    for (int it = 0; it < 8; ++it) {
      int c = it * 256 + tid;
      int o8 = (c >> 7) << 3;           // 0,8,...,120
      int pl = c & 127;
      s16x8 v = *(const s16x8*)(Tr + pl * 136 + o8);
      int pg = p0 + pl;
      int h = pg >> 6, w = pg & 63;
      int s1 = h & 3, h0 = h >> 2, s2 = w & 3, w0 = w >> 2;
      int wwin = s1 * 4 + s2, l = h0 * 16 + w0;
      int o = o0 + o8;
      int nh = o >> 5, kb = (o & 31) >> 3;
      int winbase = (b * NH + nh) * 16 + wwin;
      *(s16x8*)(dst + winbase * 8192 + (kb * 256 + l) * 8) = v;
    }
  } else {
    // V: fragment-ordered layout, 16B stores
    int d128 = tid >> 1;                // o_local 0..127
    int h_idx = tid & 1;
    int o = o0 + d128;
    int nh2 = o >> 5, d = o & 31;
    int hh = (p0 >> 6) + h_idx;
    int s1e = hh & 3, h0e = hh >> 2;
#pragma unroll
    for (int j = 0; j < 8; ++j) {
      int s2e = j & 3, woct = j >> 2;
      s16x8 v;
#pragma unroll
      for (int k = 0; k < 8; ++k) {
        int pl = h_idx * 64 + s2e + 32 * woct + 4 * k;
        v[k] = Tr[pl * 136 + d128];
      }
      int wwin = s1e * 4 + s2e;
      int l_oct = h0e * 2 + woct;       // l = l_oct*8 + k
      int winbase = (b * NH + nh2) * 16 + wwin;
      int idx = (l_oct >> 2) * 1024 + (l_oct & 3) * 256 + (d >> 4) * 128 + (d & 15) * 8;
      *(s16x8*)(ws + VOFF + winbase * 8192 + idx) = v;
    }
  }
}

// ---------------- attention kernel ----------------
// one block per (b, nh, s1, s2, qh); 4 waves, wave wv owns 32 q-rows.
// PV computed TRANSPOSED (out^T[d][l]); V read via fragment-ordered coalesced loads.
__global__ void __launch_bounds__(256, 4)
attn_kernel(const short* __restrict__ ws, const float* __restrict__ mq,
            const float* __restrict__ mk, float* __restrict__ out) {
  __shared__ s16x8 KsV[1024];   // [kb4][l256]          16KB
  __shared__ s16x8 PsV[512];    // [wave][koct4][row32] 8KB
  __shared__ float amaskS[256];
  __shared__ float mqS[128];
  __shared__ float facS[128];
  __shared__ int anyS[4];

  int bid = blockIdx.x;
  int orig = (bid & 7) * 128 + (bid >> 3);   // XCD-chunked swizzle (1024 = 8*128)
  int qh = orig & 1;
  int s2 = (orig >> 1) & 3, s1 = (orig >> 3) & 3, nh = (orig >> 5) & 7, b = orig >> 8;
  int wwin = s1 * 4 + s2;
  int tid = threadIdx.x;
  int lane = tid & 63, wv = tid >> 6, g = lane >> 4, li = lane & 15;

  int winbase = (b * NH + nh) * 16 + wwin;
  const short* qt = ws + winbase * 8192;
  const short* kt = ws + KOFF + winbase * 8192;
  const short* vt = ws + VOFF + winbase * 8192;

#pragma unroll
  for (int i = 0; i < 4; ++i) {
    int seg = i * 4 + wv;
    gload_lds16(kt + (seg * 64 + lane) * 8, &KsV[seg * 64]);
  }

  {
    int l = tid;
    int h = (l >> 4) * 4 + s1, w = (l & 15) * 4 + s2;
    float mkv = mk[b * HW + h * 64 + w];
    amaskS[l] = (mkv > 0.5f) ? 0.0f : -1e30f;
    unsigned long long bal = __ballot(mkv > 0.5f);
    if (lane == 0) anyS[wv] = (bal != 0ULL) ? 1 : 0;
  }
  if (tid < 128) {
    int l = qh * 128 + tid;
    int h = (l >> 4) * 4 + s1, w = (l & 15) * 4 + s2;
    mqS[tid] = mq[b * HW + h * 64 + w];
  }

  int lq0 = wv * 32;
  s16x8 qa[2];
#pragma unroll
  for (int m = 0; m < 2; ++m)
    qa[m] = *(const s16x8*)(qt + (g * 256 + qh * 128 + lq0 + m * 16 + li) * 8);

  __syncthreads();
  int anyk = anyS[0] | anyS[1] | anyS[2] | anyS[3];

  const f32x4 fzero = {0.f, 0.f, 0.f, 0.f};
  f32x4 of[2][2];
#pragma unroll
  for (int m = 0; m < 2; ++m) { of[m][0] = fzero; of[m][1] = fzero; }
  float rs[8];
#pragma unroll
  for (int i = 0; i < 8; ++i) rs[i] = 0.0f;

  const float C = 0.17677669529663689f * 1.4426950408889634f;

#pragma unroll
  for (int lkb = 0; lkb < 4; ++lkb) {
    f32x4 sa[2][4];
#pragma unroll
    for (int n = 0; n < 4; ++n) {
      s16x8 kf = KsV[g * 256 + lkb * 64 + n * 16 + li];
#pragma unroll
      for (int m = 0; m < 2; ++m)
        sa[m][n] = __builtin_amdgcn_mfma_f32_16x16x32_bf16(qa[m], kf, fzero, 0, 0, 0);
    }
#pragma unroll
    for (int ks = 0; ks < 2; ++ks) {
#pragma unroll
      for (int n2 = 0; n2 < 2; ++n2) {
        int n = ks * 2 + n2;
        float am = amaskS[lkb * 64 + n * 16 + li];
#pragma unroll
        for (int m = 0; m < 2; ++m) {
#pragma unroll
          for (int rr = 0; rr < 4; ++rr) {
            float pval = exp2f(sa[m][n][rr] * C + am);
            rs[m * 4 + rr] += pval;
            int row = m * 16 + g * 4 + rr;
            int cl = n * 16 + li;
            int kbh = (cl >> 3) & 3;
            short* ps = (short*)&PsV[wv * 128 + kbh * 32 + row];
            ps[cl & 7] = f2bf(pval);
          }
        }
      }
      // transposed PV: V fragments now contiguous per 16-lane group
      int kg = lkb * 2 + ks;
      s16x8 pb[2];
#pragma unroll
      for (int n = 0; n < 2; ++n) pb[n] = PsV[wv * 128 + g * 32 + n * 16 + li];
#pragma unroll
      for (int m2 = 0; m2 < 2; ++m2) {
        s16x8 va = *(const s16x8*)(vt + (kg * 4 + g) * 256 + m2 * 128 + li * 8);
#pragma unroll
        for (int n = 0; n < 2; ++n)
          of[m2][n] = __builtin_amdgcn_mfma_f32_16x16x32_bf16(va, pb[n], of[m2][n], 0, 0, 0);
      }
    }
  }

#pragma unroll
  for (int i = 0; i < 8; ++i) {
    float v = rs[i];
    v += __shfl_xor(v, 1);
    v += __shfl_xor(v, 2);
    v += __shfl_xor(v, 4);
    v += __shfl_xor(v, 8);
    rs[i] = v;
  }
  if (li == 0) {
#pragma unroll
    for (int m = 0; m < 2; ++m)
#pragma unroll
      for (int rr = 0; rr < 4; ++rr) {
        int row = m * 16 + g * 4 + rr;
        float sum = rs[m * 4 + rr];
        facS[wv * 32 + row] = (anyk && mqS[wv * 32 + row] > 0.5f) ? (1.0f / sum) : 0.0f;
      }
  }

#pragma unroll
  for (int m2 = 0; m2 < 2; ++m2) {
#pragma unroll
    for (int n = 0; n < 2; ++n) {
      int lloc = wv * 32 + n * 16;
      float fac = facS[lloc + li];
      int l = qh * 128 + lloc;
      int h = (l >> 4) * 4 + s1;
      int w = li * 4 + s2;
#pragma unroll
      for (int rr = 0; rr < 4; ++rr) {
        int o = nh * 32 + m2 * 16 + g * 4 + rr;
        out[((b * 256 + o) * 64 + h) * 64 + w] = of[m2][n][rr] * fac;
      }
    }
  }
}

extern "C" void kernel_launch(void* const* d_in, const int* in_sizes, int n_in,
                              void* d_out, int out_size, void* d_ws, size_t ws_size,
                              hipStream_t stream) {
  const float* fq = (const float*)d_in[0];
  const float* fk = (const float*)d_in[1];
  const float* fv = (const float*)d_in[2];
  const float* mq = (const float*)d_in[3];
  const float* mk = (const float*)d_in[4];
  const float* qw = (const float*)d_in[5];
  const float* qb = (const float*)d_in[6];
  const float* kw = (const float*)d_in[7];
  const float* kb = (const float*)d_in[8];
  const float* vw = (const float*)d_in[9];
  const float* vb = (const float*)d_in[10];
  short* ws = (short*)d_ws;   // Qw[0,8MB) Kw[8,16MB) VT[16,24MB) Wt[24,24.75MB)

  wconv_kernel<<<96, 256, 0, stream>>>(qw, kw, vw, ws);
  proj_kernel<<<768, 256, 0, stream>>>(fq, fk, fv, qb, kb, vb, ws);
  attn_kernel<<<1024, 256, 0, stream>>>(ws, mq, mk, (float*)d_out);
}

// Round 13
// 47.640 us; speedup vs baseline: 1.1807x; 1.0202x over previous
//
#include <hip/hip_runtime.h>
#include <hip/hip_bf16.h>

#define NH 8
#define DH 32
#define LW 256
#define HW 4096
#define CIN 256

typedef float f32x4 __attribute__((ext_vector_type(4)));
typedef short s16x8 __attribute__((ext_vector_type(8)));
typedef short s16x4 __attribute__((ext_vector_type(4)));

#define AS1 __attribute__((address_space(1)))
#define AS3 __attribute__((address_space(3)))

__device__ __forceinline__ short f2bf(float f) {
  __hip_bfloat16 h = __float2bfloat16(f);   // RNE
  short s; __builtin_memcpy(&s, &h, 2); return s;
}

__device__ __forceinline__ void gload_lds16(const void* g, void* l) {
  __builtin_amdgcn_global_load_lds((const AS1 void*)g, (AS3 void*)l, 16, 0, 0);
}

// ws layouts (bf16 shorts), per window (winbase = (b*NH+nh)*16 + wwin, 8192 shorts/win):
//   Q_ws / K_ws: [kb=d>>3][l 256][d&7 8]
//   V_ws: fragment-ordered: idx = (l>>3)*256 + ((d&31)>>4)*128 + (d&15)*8 + (l&7)
//   Wt (bf16 weights, k-major): [t 3][kb 32][o 256][8]  at WTOFF
#define KOFF 4194304
#define VOFF 8388608
#define WTOFF 12582912

// ---------------- weight pre-convert kernel ----------------
__global__ void wconv_kernel(const float* __restrict__ qw, const float* __restrict__ kw,
                             const float* __restrict__ vw, short* __restrict__ ws) {
  int blk = blockIdx.x;
  int t = blk >> 5, kb = blk & 31;
  const float* W = (t == 0) ? qw : ((t == 1) ? kw : vw);
  int o = threadIdx.x;
  f32x4 w0 = *(const f32x4*)(W + o * CIN + kb * 8);
  f32x4 w1 = *(const f32x4*)(W + o * CIN + kb * 8 + 4);
  s16x8 v;
#pragma unroll
  for (int j = 0; j < 4; ++j) { v[j] = f2bf(w0[j]); v[4 + j] = f2bf(w1[j]); }
  *(s16x8*)(ws + WTOFF + (blk * 256 + o) * 8) = v;
}

// ---------------- projection kernel ----------------
// tile BM=256(o, ALL channels) x BN=64(p = one h-row) x BK=64; 4 waves;
// wave wv owns o-rows [wv*64, wv*64+64). fea read EXACTLY ONCE chip-wide.
// A-frags direct from L2-hot Wt; B double-buffered in LDS (light: 16 floats/thread).
__global__ void __launch_bounds__(256, 3)
proj_kernel(const float* __restrict__ fq, const float* __restrict__ fk,
            const float* __restrict__ fv,
            const float* __restrict__ qb, const float* __restrict__ kb_,
            const float* __restrict__ vb,
            short* __restrict__ ws) {
  __shared__ s16x8 SMEM[2112];   // GEMM: B dbuf [2][512] (16KB); epilogue: Tr [64][264] shorts (33.8KB)

  int bid = blockIdx.x;
  int orig = (bid & 7) * 96 + (bid >> 3);   // XCD-chunked swizzle (768 = 8*96)
  int t = orig >> 8;                        // 0:Q 1:K 2:V
  int r0 = orig & 255;
  int b = r0 >> 6;
  int pblk = r0 & 63;                       // = global h row

  const float* fea = (t == 0) ? fq : ((t == 1) ? fk : fv);
  const float* Bv  = (t == 0) ? qb : ((t == 1) ? kb_ : vb);
  const short* Wt  = ws + WTOFF + t * 65536;   // [kb 32][o 256][8]

  int p0 = pblk * 64;
  int tid = threadIdx.x;
  int lane = tid & 63, wv = tid >> 6;
  int g = lane >> 4, li = lane & 15;

  const f32x4 fzero = {0.f, 0.f, 0.f, 0.f};
  f32x4 acc[4][4];
#pragma unroll
  for (int m = 0; m < 4; ++m)
#pragma unroll
    for (int n = 0; n < 4; ++n) acc[m][n] = fzero;

  const float* feab = fea + b * (CIN * HW);
  int wq = tid & 15;             // w-quad 0..15
  int jh = (tid >> 4) & 1;       // c-half within octet
  int coct = tid >> 5;           // c octet 0..7

  f32x4 ldB[4];

#define LOAD_B(cs_) do { int c0_ = (cs_) * 64; _Pragma("unroll") \
  for (int j_ = 0; j_ < 4; ++j_) \
    ldB[j_] = *(const f32x4*)(feab + (c0_ + coct * 8 + jh * 4 + j_) * HW + p0 + wq * 4); } while (0)

#define WRITE_B(buf_) do { _Pragma("unroll") \
  for (int pp_ = 0; pp_ < 4; ++pp_) { s16x4 v_; _Pragma("unroll") \
    for (int j_ = 0; j_ < 4; ++j_) v_[j_] = f2bf(ldB[j_][pp_]); \
    int w_ = wq * 4 + pp_; int wsw_ = w_ ^ ((w_ >> 3) & 7); \
    *(s16x4*)((short*)SMEM + ((buf_) * 512 + coct * 64 + wsw_) * 8 + jh * 4) = v_; } } while (0)

  // prologue
  LOAD_B(0);
  WRITE_B(0);
  __syncthreads();

#pragma unroll
  for (int cs = 0; cs < 4; ++cs) {
    if (cs < 3) LOAD_B(cs + 1);
    // batch-load this cs's A-fragments (L2-hot Wt), then compute
    s16x8 aF[2][4];
#pragma unroll
    for (int kk = 0; kk < 2; ++kk)
#pragma unroll
      for (int m = 0; m < 4; ++m)
        aF[kk][m] = *(const s16x8*)(Wt + ((cs * 8 + kk * 4 + g) * 256 + wv * 64 + m * 16 + li) * 8);
#pragma unroll
    for (int kk = 0; kk < 2; ++kk) {
#pragma unroll
      for (int n = 0; n < 4; ++n) {
        int w = n * 16 + li;
        int wsw = w ^ ((w >> 3) & 7);
        s16x8 bb = SMEM[(cs & 1) * 512 + (kk * 4 + g) * 64 + wsw];
#pragma unroll
        for (int m = 0; m < 4; ++m)
          acc[m][n] = __builtin_amdgcn_mfma_f32_16x16x32_bf16(aF[kk][m], bb, acc[m][n], 0, 0, 0);
      }
    }
    if (cs < 3) {
      WRITE_B((cs + 1) & 1);
      __syncthreads();
    }
  }
#undef LOAD_B
#undef WRITE_B

  // ---- epilogue: bias + LDS transpose Tr[w 64][o 256 pad->264] + coalesced stores ----
  float bias_r[4][4];
#pragma unroll
  for (int m = 0; m < 4; ++m) {
    f32x4 b4 = *(const f32x4*)(Bv + wv * 64 + m * 16 + g * 4);
#pragma unroll
    for (int rr = 0; rr < 4; ++rr) bias_r[m][rr] = b4[rr];
  }

  __syncthreads();                      // all LDS B-reads done
  short* Tr = (short*)SMEM;             // [w 64][264]
#pragma unroll
  for (int m = 0; m < 4; ++m) {
    int ob = wv * 64 + m * 16 + g * 4;
#pragma unroll
    for (int n = 0; n < 4; ++n) {
      int w = n * 16 + li;
      s16x4 v;
#pragma unroll
      for (int rr = 0; rr < 4; ++rr) v[rr] = f2bf(acc[m][n][rr] + bias_r[m][rr]);
      *(s16x4*)(Tr + w * 264 + ob) = v;
    }
  }
  __syncthreads();

  int s1 = pblk & 3, h0 = pblk >> 2;    // this block = one global h row
  if (t != 2) {
    // Q/K: lane = one w, 8 consecutive d -> 16B store; 16 same-s2 lanes = 256B runs
    short* dst = ws + (t == 0 ? 0 : KOFF);
#pragma unroll
    for (int it = 0; it < 8; ++it) {
      int o_oct = it * 4 + (tid >> 6);  // 0..31
      int w = tid & 63;
      s16x8 v = *(const s16x8*)(Tr + w * 264 + o_oct * 8);
      int o = o_oct * 8;
      int nh = o >> 5, kb = (o & 31) >> 3;
      int s2 = w & 3, w0 = w >> 2;
      int l = h0 * 16 + w0;
      int winbase = (b * NH + nh) * 16 + s1 * 4 + s2;
      *(s16x8*)(dst + winbase * 8192 + (kb * 256 + l) * 8) = v;
    }
  } else {
    // V: fragment-ordered, lane = one global d, 8 consecutive l -> 16B store
#pragma unroll
    for (int it = 0; it < 8; ++it) {
      int d = tid;                      // global channel 0..255
      int s2 = it & 3, w0h = it >> 2;   // w0-octet
      int l_oct = h0 * 2 + w0h;
      s16x8 v;
#pragma unroll
      for (int k = 0; k < 8; ++k) {
        int w = (w0h * 8 + k) * 4 + s2;
        v[k] = Tr[w * 264 + d];
      }
      int dh = d & 31;
      int nh2 = d >> 5;
      int winbase = (b * NH + nh2) * 16 + s1 * 4 + s2;
      int idx = l_oct * 256 + (dh >> 4) * 128 + (dh & 15) * 8;
      *(s16x8*)(ws + VOFF + winbase * 8192 + idx) = v;
    }
  }
}

// ---------------- attention kernel ----------------  [r12-verbatim]
__global__ void __launch_bounds__(256, 4)
attn_kernel(const short* __restrict__ ws, const float* __restrict__ mq,
            const float* __restrict__ mk, float* __restrict__ out) {
  __shared__ s16x8 KsV[1024];   // [kb4][l256]          16KB
  __shared__ s16x8 PsV[512];    // [wave][koct4][row32] 8KB
  __shared__ float amaskS[256];
  __shared__ float mqS[128];
  __shared__ float facS[128];
  __shared__ int anyS[4];

  int bid = blockIdx.x;
  int orig = (bid & 7) * 128 + (bid >> 3);   // XCD-chunked swizzle (1024 = 8*128)
  int qh = orig & 1;
  int s2 = (orig >> 1) & 3, s1 = (orig >> 3) & 3, nh = (orig >> 5) & 7, b = orig >> 8;
  int wwin = s1 * 4 + s2;
  int tid = threadIdx.x;
  int lane = tid & 63, wv = tid >> 6, g = lane >> 4, li = lane & 15;

  int winbase = (b * NH + nh) * 16 + wwin;
  const short* qt = ws + winbase * 8192;
  const short* kt = ws + KOFF + winbase * 8192;
  const short* vt = ws + VOFF + winbase * 8192;

#pragma unroll
  for (int i = 0; i < 4; ++i) {
    int seg = i * 4 + wv;
    gload_lds16(kt + (seg * 64 + lane) * 8, &KsV[seg * 64]);
  }

  {
    int l = tid;
    int h = (l >> 4) * 4 + s1, w = (l & 15) * 4 + s2;
    float mkv = mk[b * HW + h * 64 + w];
    amaskS[l] = (mkv > 0.5f) ? 0.0f : -1e30f;
    unsigned long long bal = __ballot(mkv > 0.5f);
    if (lane == 0) anyS[wv] = (bal != 0ULL) ? 1 : 0;
  }
  if (tid < 128) {
    int l = qh * 128 + tid;
    int h = (l >> 4) * 4 + s1, w = (l & 15) * 4 + s2;
    mqS[tid] = mq[b * HW + h * 64 + w];
  }

  int lq0 = wv * 32;
  s16x8 qa[2];
#pragma unroll
  for (int m = 0; m < 2; ++m)
    qa[m] = *(const s16x8*)(qt + (g * 256 + qh * 128 + lq0 + m * 16 + li) * 8);

  __syncthreads();
  int anyk = anyS[0] | anyS[1] | anyS[2] | anyS[3];

  const f32x4 fzero = {0.f, 0.f, 0.f, 0.f};
  f32x4 of[2][2];
#pragma unroll
  for (int m = 0; m < 2; ++m) { of[m][0] = fzero; of[m][1] = fzero; }
  float rs[8];
#pragma unroll
  for (int i = 0; i < 8; ++i) rs[i] = 0.0f;

  const float C = 0.17677669529663689f * 1.4426950408889634f;

#pragma unroll
  for (int lkb = 0; lkb < 4; ++lkb) {
    f32x4 sa[2][4];
#pragma unroll
    for (int n = 0; n < 4; ++n) {
      s16x8 kf = KsV[g * 256 + lkb * 64 + n * 16 + li];
#pragma unroll
      for (int m = 0; m < 2; ++m)
        sa[m][n] = __builtin_amdgcn_mfma_f32_16x16x32_bf16(qa[m], kf, fzero, 0, 0, 0);
    }
#pragma unroll
    for (int ks = 0; ks < 2; ++ks) {
#pragma unroll
      for (int n2 = 0; n2 < 2; ++n2) {
        int n = ks * 2 + n2;
        float am = amaskS[lkb * 64 + n * 16 + li];
#pragma unroll
        for (int m = 0; m < 2; ++m) {
#pragma unroll
          for (int rr = 0; rr < 4; ++rr) {
            float pval = exp2f(sa[m][n][rr] * C + am);
            rs[m * 4 + rr] += pval;
            int row = m * 16 + g * 4 + rr;
            int cl = n * 16 + li;
            int kbh = (cl >> 3) & 3;
            short* ps = (short*)&PsV[wv * 128 + kbh * 32 + row];
            ps[cl & 7] = f2bf(pval);
          }
        }
      }
      int kg = lkb * 2 + ks;
      s16x8 pb[2];
#pragma unroll
      for (int n = 0; n < 2; ++n) pb[n] = PsV[wv * 128 + g * 32 + n * 16 + li];
#pragma unroll
      for (int m2 = 0; m2 < 2; ++m2) {
        s16x8 va = *(const s16x8*)(vt + (kg * 4 + g) * 256 + m2 * 128 + li * 8);
#pragma unroll
        for (int n = 0; n < 2; ++n)
          of[m2][n] = __builtin_amdgcn_mfma_f32_16x16x32_bf16(va, pb[n], of[m2][n], 0, 0, 0);
      }
    }
  }

#pragma unroll
  for (int i = 0; i < 8; ++i) {
    float v = rs[i];
    v += __shfl_xor(v, 1);
    v += __shfl_xor(v, 2);
    v += __shfl_xor(v, 4);
    v += __shfl_xor(v, 8);
    rs[i] = v;
  }
  if (li == 0) {
#pragma unroll
    for (int m = 0; m < 2; ++m)
#pragma unroll
      for (int rr = 0; rr < 4; ++rr) {
        int row = m * 16 + g * 4 + rr;
        float sum = rs[m * 4 + rr];
        facS[wv * 32 + row] = (anyk && mqS[wv * 32 + row] > 0.5f) ? (1.0f / sum) : 0.0f;
      }
  }

#pragma unroll
  for (int m2 = 0; m2 < 2; ++m2) {
#pragma unroll
    for (int n = 0; n < 2; ++n) {
      int lloc = wv * 32 + n * 16;
      float fac = facS[lloc + li];
      int l = qh * 128 + lloc;
      int h = (l >> 4) * 4 + s1;
      int w = li * 4 + s2;
#pragma unroll
      for (int rr = 0; rr < 4; ++rr) {
        int o = nh * 32 + m2 * 16 + g * 4 + rr;
        out[((b * 256 + o) * 64 + h) * 64 + w] = of[m2][n][rr] * fac;
      }
    }
  }
}

extern "C" void kernel_launch(void* const* d_in, const int* in_sizes, int n_in,
                              void* d_out, int out_size, void* d_ws, size_t ws_size,
                              hipStream_t stream) {
  const float* fq = (const float*)d_in[0];
  const float* fk = (const float*)d_in[1];
  const float* fv = (const float*)d_in[2];
  const float* mq = (const float*)d_in[3];
  const float* mk = (const float*)d_in[4];
  const float* qw = (const float*)d_in[5];
  const float* qb = (const float*)d_in[6];
  const float* kw = (const float*)d_in[7];
  const float* kb = (const float*)d_in[8];
  const float* vw = (const float*)d_in[9];
  const float* vb = (const float*)d_in[10];
  short* ws = (short*)d_ws;   // Qw[0,8MB) Kw[8,16MB) VT[16,24MB) Wt[24,24.75MB)

  wconv_kernel<<<96, 256, 0, stream>>>(qw, kw, vw, ws);
  proj_kernel<<<768, 256, 0, stream>>>(fq, fk, fv, qb, kb, vb, ws);
  attn_kernel<<<1024, 256, 0, stream>>>(ws, mq, mk, (float*)d_out);
}